// Round 8
// baseline (683.643 us; speedup 1.0000x reference)
//
#include <hip/hip_runtime.h>

typedef float f32x4 __attribute__((ext_vector_type(4)));
typedef _Float16 f16x8 __attribute__((ext_vector_type(8)));
typedef _Float16 f16x4 __attribute__((ext_vector_type(4)));
typedef _Float16 f16x2 __attribute__((ext_vector_type(2)));

#define NB 256
#define NL 256
#define NIN 256
#define ND 128
#define NH 64
#define CH 16                        // X-chunk (steps)

// raw barrier: LDS-only drain — global ops float across it
#define BAR_LDS() asm volatile("s_waitcnt lgkmcnt(0)\n\ts_barrier" ::: "memory")

// =====================================================================
// Kernel W: pack w_r|w_z|w_h (f32 [128][256]) into f16 fragment order.
// wpk[((nt*8+kc)*64+lane)*8+j] = w_gate[(nt&7)*16+(lane&15)]
//                                 [kc*32+(lane>>4)*8+j];  192 KB, L2-hot.
// =====================================================================
__global__ void kwpack_kernel(const float* __restrict__ w_r,
                              const float* __restrict__ w_z,
                              const float* __restrict__ w_h,
                              _Float16* __restrict__ wpk) {
  const int lane = threadIdx.x;        // 0..63
  const int nt = blockIdx.x;           // 0..23
  const int kc = blockIdx.y;           // 0..7
  const float* wg = (nt < 8) ? w_r : (nt < 16) ? w_z : w_h;
  const int col = (nt & 7) * 16 + (lane & 15);
  const int k0 = kc * 32 + (lane >> 4) * 8;
  const float4* p = (const float4*)(wg + (size_t)col * NIN + k0);
  float4 v0 = p[0], v1 = p[1];
  f16x8 f;
  f[0] = (_Float16)v0.x; f[1] = (_Float16)v0.y;
  f[2] = (_Float16)v0.z; f[3] = (_Float16)v0.w;
  f[4] = (_Float16)v1.x; f[5] = (_Float16)v1.y;
  f[6] = (_Float16)v1.z; f[7] = (_Float16)v1.w;
  *(f16x8*)&wpk[(((size_t)nt * 8 + kc) * 64 + lane) * 8] = f;
}

// =====================================================================
// Kernel C v15: v14 with the launch-bounds semantics DECODED.
//  R6/R7 evidence: __launch_bounds__(1024, 4) -> VGPR cap exactly 64 =
//  512 / (8 waves/SIMD). That matches CUDA semantics for the 2nd arg:
//  MIN BLOCKS PER CU. 4 blocks x 16 waves = 64 waves/CU -> clamped to
//  the HW max 32 waves/CU = 8 waves/SIMD -> cap 64 -> spills (static
//  need ~110). FIX: __launch_bounds__(1024, 1): 1 block/CU = 16 waves
//  = 4 waves/SIMD -> cap 128. HIST_PAD kept so a 2nd co-resident block
//  is impossible (no incentive to squeeze registers). Scheduling
//  byte-identical to v13/v14 (functionally verified 3x).
// =====================================================================
#define HIST_PAD 7168                 // f16 elems: pushes LDS > 80KB

__global__ __launch_bounds__(1024, 1) void kscan_kernel(
    const float* __restrict__ u_r, const float* __restrict__ u_z,
    const float* __restrict__ u_h, const float* __restrict__ b_r,
    const float* __restrict__ b_z, const float* __restrict__ b_h,
    const int* __restrict__ cor, const float* __restrict__ x,
    const _Float16* __restrict__ wpk, const float* __restrict__ k1k2,
    float* __restrict__ out) {
  const int b = blockIdx.x;
  const int tid = threadIdx.x;
  const int lane = tid & 63;
  const int w = tid >> 6;        // 0..15
  const bool scanw = (w < 8);    // waves 0..7 scan, 8..15 projection
  const int pw = w - 8;          // proj wave id 0..7
  const int quad = lane >> 4;
  const int l16 = lane & 15;
  const int q8 = quad * 8;

  __shared__ __align__(16) _Float16 hist[(NL + 1) * NH + HIST_PAD]; // 47232 B
  __shared__ __align__(16) _Float16 Xl[2 * 3 * CH * ND];   // 24576 B
  __shared__ __align__(16) _Float16 Axt[16 * 264];         // 8448 B (pad 264)
  __shared__ __align__(16) _Float16 hprev16[2][NH];        // 256 B (parity)
  __shared__ float sA[NL];                                 // 1024 B
  __shared__ int sIeff[NL];                                // 1024 B
  __shared__ float k12[NIN];                               // 1024 B

  const size_t rowb = (size_t)b * NL;

  // ---- scan waves: U fragments; n = 16w+l16, k = kk*32+q8+j ----
  f16x8 bf[3][4];
  if (scanw) {
#pragma unroll
    for (int g = 0; g < 3; ++g) {
      const float* ug = (g == 0) ? u_r : (g == 1) ? u_z : u_h;
      const float* base = ug + (size_t)(16 * w + l16) * ND;
#pragma unroll
      for (int kk = 0; kk < 4; ++kk) {
        const float4* p = (const float4*)(base + kk * 32 + q8);
        float4 v0 = p[0], v1 = p[1];
        f16x8 f;
        f[0] = (_Float16)v0.x; f[1] = (_Float16)v0.y;
        f[2] = (_Float16)v0.z; f[3] = (_Float16)v0.w;
        f[4] = (_Float16)v1.x; f[5] = (_Float16)v1.y;
        f[6] = (_Float16)v1.z; f[7] = (_Float16)v1.w;
        bf[g][kk] = f;
      }
    }
  }

  if (tid < NH) { hprev16[0][tid] = (_Float16)0.f; hist[tid] = (_Float16)0.f; }
  if (tid < NL) {
    const int c = cor[rowb + tid];
    sIeff[tid] = (c == 0) ? tid : c;
  }
  if (tid < NIN) k12[tid] = k1k2[tid] - k1k2[NIN + tid];

  // ---- proj-wave machinery ----
  const int prow0 = 2 * pw;            // chunk-local rows this wave stages
  float4 xrA0, xrB0;                   // staged x rows (4 f32/lane each)
  f16x8 bfr[8];                        // W-frags for one n-tile

  auto LOADX = [&](int t0) {
    const float4* pa = (const float4*)(x + (rowb + t0 + prow0) * NIN + lane * 4);
    const float4* pb = (const float4*)(x + (rowb + t0 + prow0 + 1) * NIN + lane * 4);
    xrA0 = pa[0];
    xrB0 = pb[0];
  };
  auto STAGEX = [&](int t0) {
    f16x4 ha, hb;
    ha[0] = (_Float16)xrA0.x; ha[1] = (_Float16)xrA0.y;
    ha[2] = (_Float16)xrA0.z; ha[3] = (_Float16)xrA0.w;
    hb[0] = (_Float16)xrB0.x; hb[1] = (_Float16)xrB0.y;
    hb[2] = (_Float16)xrB0.z; hb[3] = (_Float16)xrB0.w;
    *(f16x4*)&Axt[prow0 * 264 + lane * 4] = ha;
    *(f16x4*)&Axt[(prow0 + 1) * 264 + lane * 4] = hb;
    const float4 kk = *(const float4*)&k12[lane * 4];
    float pa = xrA0.x * kk.x + xrA0.y * kk.y + xrA0.z * kk.z + xrA0.w * kk.w;
    float pb = xrB0.x * kk.x + xrB0.y * kk.y + xrB0.z * kk.z + xrB0.w * kk.w;
#pragma unroll
    for (int s = 1; s < 64; s <<= 1) {
      pa += __shfl_xor(pa, s);
      pb += __shfl_xor(pb, s);
    }
    if (lane == 0) {
      sA[t0 + prow0] = 1.f / (1.f + __expf(-pa));
      sA[t0 + prow0 + 1] = 1.f / (1.f + __expf(-pb));
    }
  };
  auto LOADB = [&](int i) {
    const int nt = pw * 3 + i;
#pragma unroll
    for (int kk = 0; kk < 8; ++kk)
      bfr[kk] = *(const f16x8*)&wpk[(((size_t)nt * 8 + kk) * 64 + lane) * 8];
  };
  auto GEMMG = [&](int i, int buf) {
    const int nt = pw * 3 + i;
    const int g = nt >> 3;
    const int dblk = nt & 7;
    f32x4 accP = (f32x4){0.f, 0.f, 0.f, 0.f};
#pragma unroll
    for (int kk = 0; kk < 8; ++kk) {
      f16x8 af = *(const f16x8*)&Axt[l16 * 264 + kk * 32 + q8];
      accP = __builtin_amdgcn_mfma_f32_16x16x32_f16(af, bfr[kk], accP, 0, 0, 0);
    }
    _Float16* xd = &Xl[((buf * 3 + g) * CH + quad * 4) * ND + dblk * 16 + l16];
#pragma unroll
    for (int r = 0; r < 4; ++r) xd[r * ND] = (_Float16)accP[r];
  };

  // ---- prologue: proj waves build chunk 0 ----
  if (!scanw) LOADX(0);
  __syncthreads();                     // k12 / LDS inits visible
  if (!scanw) STAGEX(0);
  __syncthreads();                     // Axt + sA[0..15] visible
  if (!scanw) {
    LOADB(0); GEMMG(0, 0);
    LOADB(1); GEMMG(1, 0);
    LOADB(2); GEMMG(2, 0);
  }

  const bool owner = scanw && (quad == 0);
  const int d = 16 * w + l16;          // scan: one d per owner lane
  float bbv[3] = {0.f, 0.f, 0.f};
  if (owner) { bbv[0] = b_r[d]; bbv[1] = b_z[d]; bbv[2] = b_h[d]; }
  __syncthreads();                     // Xl buf 0 visible

  // ---- scan per-step state ----
  const f32x4 kZ = (f32x4){0.f, 0.f, 0.f, 0.f};
  float a_c = 0.f;
  int ieff_c = 0;
  bool pf_c = true;
  float hp = 0.f;
  f32x4 accL[3], accH[3];
  if (scanw) {
    a_c = sA[0];
    ieff_c = sIeff[0];
#pragma unroll
    for (int g = 0; g < 3; ++g) { accL[g] = kZ; accH[g] = kZ; }
  }

  for (int t = 0; t < NL; ++t) {
    const int cur = (t >> 4) & 1;
    const int tin = t & 15;

    if (scanw) {
      const int par = t & 1;
      const float a = a_c;
      const float oma = 1.f - a;
      const int ieff = ieff_c;

      // ---- late-H path: hist row only became readable at this barrier ----
      if (!pf_c) {
        f16x8 g2 = *(const f16x8*)&hist[ieff * NH + q8];
        f16x8 g3 = *(const f16x8*)&hist[ieff * NH + 32 + q8];
#pragma unroll
        for (int g = 0; g < 3; ++g) {
          accH[g] = __builtin_amdgcn_mfma_f32_16x16x32_f16(g2, bf[g][2], kZ, 0, 0, 0);
          accH[g] = __builtin_amdgcn_mfma_f32_16x16x32_f16(g3, bf[g][3], accH[g], 0, 0, 0);
        }
      }

      // ---- L-half (critical): raw h_{t-1} ----
      f16x8 h0 = *(const f16x8*)&hprev16[par][q8];
      f16x8 h1 = *(const f16x8*)&hprev16[par][32 + q8];
#pragma unroll
      for (int g = 0; g < 3; ++g) {
        accL[g] = __builtin_amdgcn_mfma_f32_16x16x32_f16(h0, bf[g][0], kZ, 0, 0, 0);
        accL[g] = __builtin_amdgcn_mfma_f32_16x16x32_f16(h1, bf[g][1], accL[g], 0, 0, 0);
      }

      // ---- X + md for this step (owner lanes; straight Xl layout) ----
      float xv[3], md = 0.f;
      if (owner) {
#pragma unroll
        for (int g = 0; g < 3; ++g)
          xv[g] = (float)Xl[((cur * 3 + g) * CH + tin) * ND + d];
        if (w < 4) {
          md = a * hp;
        } else if (ieff == t) {
          md = oma * hp;
        } else {
          md = oma * (float)hist[ieff * NH + (d - NH)];
        }
      }

      // ---- prefetch step-(t+1) state ----
      const int tn = (t < NL - 1) ? t + 1 : t;
      float a_n = sA[tn];
      int ieff_n = sIeff[tn];
      bool pf_n = (ieff_n <= t);

      // ---- epilogue (owner lanes): a*L + (1-a)*H in f32 ----
      if (owner) {
        float mr = a * accL[0][0] + oma * accH[0][0];
        float mz = a * accL[1][0] + oma * accH[1][0];
        float mh = a * accL[2][0] + oma * accH[2][0];
        float er = __expf(-(xv[0] + bbv[0] + mr));
        float rr = __builtin_amdgcn_rcpf(1.f + er);
        float ez = __expf(-(xv[1] + bbv[1] + mz));
        float zz = __builtin_amdgcn_rcpf(1.f + ez);
        float e2 = __expf(2.f * (xv[2] + bbv[2] + rr * mh));
        float hh = (e2 - 1.f) * __builtin_amdgcn_rcpf(e2 + 1.f);
        float h = md + zz * (hh - md);   // (1-z)*m + z*hh
        hp = h;
        out[(rowb + t) * ND + d] = h;    // never drained per-step
        if (d < NH) hprev16[par ^ 1][d] = (_Float16)h;
        else        hist[(t + 1) * NH + (d - NH)] = (_Float16)h;
      }

      // ---- pre-issue next step's H half if its hist row is stable ----
      if (pf_n) {
        f16x8 g2 = *(const f16x8*)&hist[ieff_n * NH + q8];
        f16x8 g3 = *(const f16x8*)&hist[ieff_n * NH + 32 + q8];
#pragma unroll
        for (int g = 0; g < 3; ++g) {
          accH[g] = __builtin_amdgcn_mfma_f32_16x16x32_f16(g2, bf[g][2], kZ, 0, 0, 0);
          accH[g] = __builtin_amdgcn_mfma_f32_16x16x32_f16(g3, bf[g][3], accH[g], 0, 0, 0);
        }
      }

      a_c = a_n; ieff_c = ieff_n; pf_c = pf_n;
    } else {
      // ---- projection waves: build chunk t0n into Xl[cur^1] ----
      const int t0n = (t & ~15) + 16;
      if (t0n < NL) {
        if (tin == 0)      LOADX(t0n);
        else if (tin == 2) STAGEX(t0n);
        else if (tin == 3) LOADB(0);
        else if (tin == 4) { GEMMG(0, cur ^ 1); LOADB(1); }
        else if (tin == 5) { GEMMG(1, cur ^ 1); LOADB(2); }
        else if (tin == 6) GEMMG(2, cur ^ 1);
      }
    }

    // ---- one barrier per step: LDS drain only ----
    BAR_LDS();
  }
}

// =====================================================================
extern "C" void kernel_launch(void* const* d_in, const int* in_sizes, int n_in,
                              void* d_out, int out_size, void* d_ws, size_t ws_size,
                              hipStream_t stream) {
  (void)in_sizes; (void)n_in; (void)out_size; (void)ws_size;
  const float* x    = (const float*)d_in[0];
  const int*   cor  = (const int*)d_in[1];
  const float* w_r  = (const float*)d_in[2];
  const float* b_r  = (const float*)d_in[3];
  const float* u_r  = (const float*)d_in[4];
  const float* w_z  = (const float*)d_in[5];
  const float* b_z  = (const float*)d_in[6];
  const float* u_z  = (const float*)d_in[7];
  const float* w_h  = (const float*)d_in[8];
  const float* b_h  = (const float*)d_in[9];
  const float* u_h  = (const float*)d_in[10];
  const float* k1k2 = (const float*)d_in[11];

  _Float16* wpk = (_Float16*)d_ws;   // 192 KB, L2-hot

  kwpack_kernel<<<dim3(24, 8), dim3(64), 0, stream>>>(w_r, w_z, w_h, wpk);
  kscan_kernel<<<dim3(NB), dim3(1024), 0, stream>>>(u_r, u_z, u_h, b_r, b_z,
                                                    b_h, cor, x, wpk, k1k2,
                                                    (float*)d_out);
}

// Round 10
// 301.375 us; speedup vs baseline: 2.2684x; 2.2684x over previous
//
#include <hip/hip_runtime.h>

typedef float f32x4 __attribute__((ext_vector_type(4)));
typedef _Float16 f16x8 __attribute__((ext_vector_type(8)));
typedef _Float16 f16x2 __attribute__((ext_vector_type(2)));

#define NB 256
#define NL 256
#define NIN 256
#define ND 128
#define NH 64
#define BL (NB * NL)                 // 65536 rows
#define BLD ((size_t)BL * ND)        // 8,388,608 elements per gate
#define CH 16                        // X-staging chunk (steps)

// raw barrier: LDS-only drain (no vmcnt) — global ops float across it.
// sched_barrier(0) after the asm: hipcc is known to hoist ops past an
// inline-asm s_waitcnt despite the "memory" clobber (gfx950 rule #18);
// the compile-time fence forbids any instruction from crossing.
#define BAR_LDS()                                                     \
  do {                                                                \
    asm volatile("s_waitcnt lgkmcnt(0)\n\ts_barrier" ::: "memory");   \
    __builtin_amdgcn_sched_barrier(0);                                \
  } while (0)

__device__ __forceinline__ void gload_lds16(const _Float16* gp, _Float16* lp) {
  __builtin_amdgcn_global_load_lds(
      (const __attribute__((address_space(1))) void*)gp,
      (__attribute__((address_space(3))) void*)lp, 16, 0, 0);
}

// =====================================================================
// Kernel W: pack w_r|w_z|w_h (f32 [128][256]) into f16 fragment order.
// =====================================================================
__global__ void kwpack_kernel(const float* __restrict__ w_r,
                              const float* __restrict__ w_z,
                              const float* __restrict__ w_h,
                              _Float16* __restrict__ wpk) {
  const int lane = threadIdx.x;        // 0..63
  const int nt = blockIdx.x;           // 0..23
  const int kc = blockIdx.y;           // 0..7
  const float* wg = (nt < 8) ? w_r : (nt < 16) ? w_z : w_h;
  const int col = (nt & 7) * 16 + (lane & 15);
  const int k0 = kc * 32 + (lane >> 4) * 8;
  const float4* p = (const float4*)(wg + (size_t)col * NIN + k0);
  float4 v0 = p[0], v1 = p[1];
  f16x8 f;
  f[0] = (_Float16)v0.x; f[1] = (_Float16)v0.y;
  f[2] = (_Float16)v0.z; f[3] = (_Float16)v0.w;
  f[4] = (_Float16)v1.x; f[5] = (_Float16)v1.y;
  f[6] = (_Float16)v1.z; f[7] = (_Float16)v1.w;
  *(f16x8*)&wpk[(((size_t)nt * 8 + kc) * 64 + lane) * 8] = f;
}

// =====================================================================
// Kernel B v6h: v6 (R4) + sched_barrier hardening after BAR_LDS.
// Layout contract with kscan: wsX[g*BLD + row*ND + pos(d)],
//   pos(d = 32q+16s+r) = 32q + s + 2r
// =====================================================================
__global__ __launch_bounds__(256, 2) void kproj_kernel(
    const float* __restrict__ x, const _Float16* __restrict__ wpk,
    const float* __restrict__ k1k2, _Float16* __restrict__ wsX,
    float* __restrict__ wsA) {
  const int r0 = blockIdx.x * 64;

  __shared__ __align__(16) _Float16 Ah[2][64 * 40];   // 10240 B
  __shared__ float k12[NIN];                          // 1024 B
  __shared__ __align__(16) _Float16 T[64 * 392];      // 50176 B transpose buf

  const int tid = threadIdx.x;
  const int lane = tid & 63;
  const int w = tid >> 6;
  const int l16 = lane & 15;
  const int quad = lane >> 4;
  const int q8 = quad * 8;

  k12[tid] = k1k2[tid] - k1k2[NIN + tid];

  const int srow = tid >> 2;          // 0..63
  const int seg = tid & 3;            // 8-float segment within 32-float kc
  const float4* xrow4 = (const float4*)(x + (size_t)(r0 + srow) * NIN + seg * 8);

  f32x4 acc[6][4];                    // [n-tile][m-tile]
#pragma unroll
  for (int i = 0; i < 6; ++i)
#pragma unroll
    for (int mt = 0; mt < 4; ++mt) acc[i][mt] = (f32x4){0.f, 0.f, 0.f, 0.f};

  // preload kc=0: x regs + B frags
  float4 xa = xrow4[0], xb = xrow4[1];
  f16x8 bcur[6], bnxt[6];
#pragma unroll
  for (int i = 0; i < 6; ++i)
    bcur[i] = *(const f16x8*)&wpk[(((size_t)(6 * w + i) * 8 + 0) * 64 + lane) * 8];

  float adot = 0.f;
  __syncthreads();                    // k12 visible

  for (int kc = 0; kc < 8; ++kc) {
    const int buf = kc & 1;
    // ---- ka partial (fp32, pre-truncation) ----
    {
      const float4* kk = (const float4*)&k12[kc * 32 + seg * 8];
      float4 k0 = kk[0], k1 = kk[1];
      adot += xa.x * k0.x + xa.y * k0.y + xa.z * k0.z + xa.w * k0.w +
              xb.x * k1.x + xb.y * k1.y + xb.z * k1.z + xb.w * k1.w;
    }
    // ---- cvt + stage x chunk ----
    {
      f16x8 h;
      h[0] = (_Float16)xa.x; h[1] = (_Float16)xa.y;
      h[2] = (_Float16)xa.z; h[3] = (_Float16)xa.w;
      h[4] = (_Float16)xb.x; h[5] = (_Float16)xb.y;
      h[6] = (_Float16)xb.z; h[7] = (_Float16)xb.w;
      *(f16x8*)&Ah[buf][srow * 40 + seg * 8] = h;
    }
    // ---- issue next-kc loads (x + B); in flight across the barrier ----
    if (kc < 7) {
      xa = xrow4[(kc + 1) * 8];
      xb = xrow4[(kc + 1) * 8 + 1];
#pragma unroll
      for (int i = 0; i < 6; ++i)
        bnxt[i] = *(const f16x8*)&wpk[(((size_t)(6 * w + i) * 8 + (kc + 1)) * 64 + lane) * 8];
    }
    BAR_LDS();   // lgkm drain only — global loads NOT drained

    // ---- A frags + MFMA ----
    f16x8 af[4];
#pragma unroll
    for (int mt = 0; mt < 4; ++mt)
      af[mt] = *(const f16x8*)&Ah[buf][(mt * 16 + l16) * 40 + q8];
#pragma unroll
    for (int i = 0; i < 6; ++i)
#pragma unroll
      for (int mt = 0; mt < 4; ++mt)
        acc[i][mt] = __builtin_amdgcn_mfma_f32_16x16x32_f16(af[mt], bcur[i], acc[i][mt], 0, 0, 0);
#pragma unroll
    for (int i = 0; i < 6; ++i) bcur[i] = bnxt[i];
  }

  // ---- ka reduce + store (lanes tid%4==0) ----
  adot += __shfl_xor(adot, 1);
  adot += __shfl_xor(adot, 2);
  if ((tid & 3) == 0) wsA[r0 + srow] = 1.f / (1.f + __expf(-adot));

  // ---- epilogue phase 1: pair-writes into T (permutation resolved in LDS)
#pragma unroll
  for (int i = 0; i < 6; i += 2) {
    const int nt = 6 * w + i;          // even; pair never straddles a gate
    const int g = nt >> 3;
    const int q = (nt & 7) >> 1;
    _Float16* trow = T + g * 128 + q * 32 + 2 * l16;
#pragma unroll
    for (int mt = 0; mt < 4; ++mt)
#pragma unroll
      for (int r = 0; r < 4; ++r) {
        const int row = mt * 16 + quad * 4 + r;   // block-local output row
        f16x2 pr;
        pr[0] = (_Float16)acc[i][mt][r];
        pr[1] = (_Float16)acc[i + 1][mt][r];
        *(f16x2*)&trow[row * 392] = pr;
      }
  }
  __syncthreads();

  // ---- epilogue phase 2: coalesced stream-out (1KB/instr) ----
#pragma unroll
  for (int g = 0; g < 3; ++g) {
    _Float16* dstg = wsX + (size_t)g * BLD + (size_t)r0 * ND;
#pragma unroll
    for (int p = 0; p < 4; ++p) {
      const int row = 16 * w + 4 * p + quad;
      const f16x8 v = *(const f16x8*)&T[row * 392 + g * 128 + l16 * 8];
      *(f16x8*)&dstg[(size_t)row * ND + l16 * 8] = v;
    }
  }
}

// =====================================================================
// Kernel C v11h: v11 (R4-verified, ~180us) + sync hardening:
//  - sched_barrier(0) after every BAR_LDS (no runtime cost).
//  - chunk boundary (tin==15) uses plain __syncthreads() — the
//    compiler-managed full drain (vmcnt+lgkm+barrier) instead of the
//    hand-rolled WAIT_VM0+BAR_LDS pair. ~+4us worst case.
// =====================================================================
__global__ __launch_bounds__(512, 2) void kscan_kernel(
    const float* __restrict__ u_r, const float* __restrict__ u_z,
    const float* __restrict__ u_h, const float* __restrict__ b_r,
    const float* __restrict__ b_z, const float* __restrict__ b_h,
    const int* __restrict__ cor, const _Float16* __restrict__ wsX,
    const float* __restrict__ wsA, float* __restrict__ out) {
  const int b = blockIdx.x;
  const int tid = threadIdx.x;
  const int lane = tid & 63;
  const int w = tid >> 6;        // wave id 0..7 -> d range [16w, 16w+16)
  const int quad = lane >> 4;
  const int l16 = lane & 15;
  const int q8 = quad * 8;

  __shared__ __align__(16) _Float16 hist[(NL + 1) * NH];   // 32896 B
  __shared__ __align__(16) _Float16 Xl[2 * 3 * CH * ND];   // 24576 B
  __shared__ __align__(16) _Float16 hprev16[2][NH];        // 256 B (parity)
  __shared__ float sA[NL];
  __shared__ int sIeff[NL];

  // ---- U fragments: u_g[n][k] f16; n = 16w+l16, k = kk*32+q8+j ----
  f16x8 bf[3][4];
#pragma unroll
  for (int g = 0; g < 3; ++g) {
    const float* ug = (g == 0) ? u_r : (g == 1) ? u_z : u_h;
    const float* base = ug + (size_t)(16 * w + l16) * ND;
#pragma unroll
    for (int kk = 0; kk < 4; ++kk) {
      const float4* p = (const float4*)(base + kk * 32 + q8);
      float4 v0 = p[0], v1 = p[1];
      f16x8 f;
      f[0] = (_Float16)v0.x; f[1] = (_Float16)v0.y;
      f[2] = (_Float16)v0.z; f[3] = (_Float16)v0.w;
      f[4] = (_Float16)v1.x; f[5] = (_Float16)v1.y;
      f[6] = (_Float16)v1.z; f[7] = (_Float16)v1.w;
      bf[g][kk] = f;
    }
  }

  const size_t rowb = (size_t)b * NL;
  if (tid < NH) { hprev16[0][tid] = (_Float16)0.f; hist[tid] = (_Float16)0.f; }
  if (tid < NL) {
    sA[tid] = wsA[rowb + tid];
    const int c = cor[rowb + tid];
    sIeff[tid] = (c == 0) ? tid : c;
  }

  // ---- chunk 0 of X into Xl buf 0: waves 0..5, 2 per gate, 2x 1KB ----
  if (w < 6) {
    const int g = w >> 1, half = w & 1;
    const _Float16* src = wsX + (size_t)g * BLD + rowb * ND + half * 1024 + lane * 8;
    _Float16* dst = &Xl[g * (CH * ND) + half * 1024];   // wave-uniform base
    gload_lds16(src, dst);
    gload_lds16(src + 512, dst + 512);
  }

  const bool owner = (quad == 0);
  const int d = 16 * w + l16;                      // one d per owner lane
  const int xpos = 32 * (w >> 1) + (w & 1) + 2 * l16;  // permuted position
  float bbv[3] = {0.f, 0.f, 0.f};
  if (owner) { bbv[0] = b_r[d]; bbv[1] = b_z[d]; bbv[2] = b_h[d]; }
  __syncthreads();   // full drain once: chunk-0 loads + LDS init visible

  // ---- pipelined per-step state ----
  const f32x4 kZ = (f32x4){0.f, 0.f, 0.f, 0.f};
  float a_c = sA[0];
  int ieff_c = sIeff[0];
  bool pf_c = true;
  float hp = 0.f;                      // own h_{t-1} (owner lanes)
  f32x4 accL[3], accH[3];
#pragma unroll
  for (int g = 0; g < 3; ++g) { accL[g] = kZ; accH[g] = kZ; }

  for (int t = 0; t < NL; ++t) {
    const int par = t & 1;
    const float a = a_c;
    const float oma = 1.f - a;
    const int ieff = ieff_c;
    const int cur = (t >> 4) & 1;
    const int tin = t & 15;

    // ---- issue next X chunk (once per 16 steps) ----
    if (tin == 0 && t + CH < NL && w < 6) {
      const int g = w >> 1, half = w & 1;
      const _Float16* src =
          wsX + (size_t)g * BLD + (rowb + t + CH) * ND + half * 1024 + lane * 8;
      _Float16* dst = &Xl[(cur ^ 1) * (3 * CH * ND) + g * (CH * ND) + half * 1024];
      gload_lds16(src, dst);
      gload_lds16(src + 512, dst + 512);
    }

    // ---- late-H path: hist row only became readable at this barrier ----
    if (!pf_c) {
      f16x8 g2 = *(const f16x8*)&hist[ieff * NH + q8];
      f16x8 g3 = *(const f16x8*)&hist[ieff * NH + 32 + q8];
#pragma unroll
      for (int g = 0; g < 3; ++g) {
        accH[g] = __builtin_amdgcn_mfma_f32_16x16x32_f16(g2, bf[g][2], kZ, 0, 0, 0);
        accH[g] = __builtin_amdgcn_mfma_f32_16x16x32_f16(g3, bf[g][3], accH[g], 0, 0, 0);
      }
    }

    // ---- L-half (critical): raw h_{t-1} ----
    f16x8 h0 = *(const f16x8*)&hprev16[par][q8];
    f16x8 h1 = *(const f16x8*)&hprev16[par][32 + q8];
#pragma unroll
    for (int g = 0; g < 3; ++g) {
      accL[g] = __builtin_amdgcn_mfma_f32_16x16x32_f16(h0, bf[g][0], kZ, 0, 0, 0);
      accL[g] = __builtin_amdgcn_mfma_f32_16x16x32_f16(h1, bf[g][1], accL[g], 0, 0, 0);
    }

    // ---- X + md for this step (owner lanes) ----
    float xv[3], md = 0.f;
    if (owner) {
      const _Float16* xp = &Xl[cur * (3 * CH * ND) + tin * ND + xpos];
#pragma unroll
      for (int g = 0; g < 3; ++g) xv[g] = (float)xp[g * (CH * ND)];
      if (w < 4) {
        md = a * hp;
      } else if (ieff == t) {
        md = oma * hp;
      } else {
        md = oma * (float)hist[ieff * NH + (d - NH)];
      }
    }

    // ---- prefetch step-(t+1) state ----
    const int tn = (t < NL - 1) ? t + 1 : t;
    float a_n = sA[tn];
    int ieff_n = sIeff[tn];
    bool pf_n = (ieff_n <= t);         // hist row readable before barrier?

    // ---- epilogue (owner lanes): combine a*L + (1-a)*H in f32 ----
    if (owner) {
      float mr = a * accL[0][0] + oma * accH[0][0];
      float mz = a * accL[1][0] + oma * accH[1][0];
      float mh = a * accL[2][0] + oma * accH[2][0];
      float er = __expf(-(xv[0] + bbv[0] + mr));
      float rr = __builtin_amdgcn_rcpf(1.f + er);
      float ez = __expf(-(xv[1] + bbv[1] + mz));
      float zz = __builtin_amdgcn_rcpf(1.f + ez);
      float e2 = __expf(2.f * (xv[2] + bbv[2] + rr * mh));
      float hh = (e2 - 1.f) * __builtin_amdgcn_rcpf(e2 + 1.f);
      float h = md + zz * (hh - md);   // (1-z)*m + z*hh
      hp = h;
      out[(rowb + t) * ND + d] = h;    // floats across BAR_LDS steps
      if (d < NH) hprev16[par ^ 1][d] = (_Float16)h;
      else        hist[(t + 1) * NH + (d - NH)] = (_Float16)h;
    }

    // ---- pre-issue next step's H half if its hist row is stable ----
    if (pf_n) {
      f16x8 g2 = *(const f16x8*)&hist[ieff_n * NH + q8];
      f16x8 g3 = *(const f16x8*)&hist[ieff_n * NH + 32 + q8];
#pragma unroll
      for (int g = 0; g < 3; ++g) {
        accH[g] = __builtin_amdgcn_mfma_f32_16x16x32_f16(g2, bf[g][2], kZ, 0, 0, 0);
        accH[g] = __builtin_amdgcn_mfma_f32_16x16x32_f16(g3, bf[g][3], accH[g], 0, 0, 0);
      }
    }

    // ---- barrier: LDS-only most steps; FULL drain at chunk boundary ----
    if (tin == 15) __syncthreads();
    else           BAR_LDS();

    a_c = a_n; ieff_c = ieff_n; pf_c = pf_n;
  }
}

// =====================================================================
extern "C" void kernel_launch(void* const* d_in, const int* in_sizes, int n_in,
                              void* d_out, int out_size, void* d_ws, size_t ws_size,
                              hipStream_t stream) {
  (void)in_sizes; (void)n_in; (void)out_size; (void)ws_size;
  const float* x    = (const float*)d_in[0];
  const int*   cor  = (const int*)d_in[1];
  const float* w_r  = (const float*)d_in[2];
  const float* b_r  = (const float*)d_in[3];
  const float* u_r  = (const float*)d_in[4];
  const float* w_z  = (const float*)d_in[5];
  const float* b_z  = (const float*)d_in[6];
  const float* u_z  = (const float*)d_in[7];
  const float* w_h  = (const float*)d_in[8];
  const float* b_h  = (const float*)d_in[9];
  const float* u_h  = (const float*)d_in[10];
  const float* k1k2 = (const float*)d_in[11];

  _Float16* wsX = (_Float16*)d_ws;                                 // 48 MB
  float* wsA = (float*)((char*)d_ws + 3 * BLD * 2);                // 256 KB
  _Float16* wpk = (_Float16*)((char*)d_ws + 3 * BLD * 2 + BL * 4); // 192 KB

  kwpack_kernel<<<dim3(24, 8), dim3(64), 0, stream>>>(w_r, w_z, w_h, wpk);
  kproj_kernel<<<dim3(BL / 64), dim3(256), 0, stream>>>(x, wpk, k1k2, wsX, wsA);
  kscan_kernel<<<dim3(NB), dim3(512), 0, stream>>>(u_r, u_z, u_h, b_r, b_z, b_h,
                                                   cor, wsX, wsA, (float*)d_out);
}

// Round 11
// 262.151 us; speedup vs baseline: 2.6078x; 1.1496x over previous
//
#include <hip/hip_runtime.h>

typedef float f32x4 __attribute__((ext_vector_type(4)));
typedef _Float16 f16x8 __attribute__((ext_vector_type(8)));
typedef _Float16 f16x4 __attribute__((ext_vector_type(4)));
typedef _Float16 f16x2 __attribute__((ext_vector_type(2)));

#define NB 256
#define NL 256
#define NIN 256
#define ND 128
#define NH 64
#define CH 16                        // X-chunk (steps)
#define AXP 280                      // Axt row stride (f16): bank-spread pad

// raw barrier: LDS-only drain + compile-time fence (R10-hardened)
#define BAR_LDS()                                                     \
  do {                                                                \
    asm volatile("s_waitcnt lgkmcnt(0)\n\ts_barrier" ::: "memory");   \
    __builtin_amdgcn_sched_barrier(0);                                \
  } while (0)

// =====================================================================
// Kernel W: pack w_r|w_z|w_h (f32 [128][256]) into f16 fragment order.
// wpk[((nt*8+kc)*64+lane)*8+j] = w_gate[(nt&7)*16+(lane&15)]
//                                 [kc*32+(lane>>4)*8+j];  192 KB, L2-hot.
// =====================================================================
__global__ void kwpack_kernel(const float* __restrict__ w_r,
                              const float* __restrict__ w_z,
                              const float* __restrict__ w_h,
                              _Float16* __restrict__ wpk) {
  const int lane = threadIdx.x;        // 0..63
  const int nt = blockIdx.x;           // 0..23
  const int kc = blockIdx.y;           // 0..7
  const float* wg = (nt < 8) ? w_r : (nt < 16) ? w_z : w_h;
  const int col = (nt & 7) * 16 + (lane & 15);
  const int k0 = kc * 32 + (lane >> 4) * 8;
  const float4* p = (const float4*)(wg + (size_t)col * NIN + k0);
  float4 v0 = p[0], v1 = p[1];
  f16x8 f;
  f[0] = (_Float16)v0.x; f[1] = (_Float16)v0.y;
  f[2] = (_Float16)v0.z; f[3] = (_Float16)v0.w;
  f[4] = (_Float16)v1.x; f[5] = (_Float16)v1.y;
  f[6] = (_Float16)v1.z; f[7] = (_Float16)v1.w;
  *(f16x8*)&wpk[(((size_t)nt * 8 + kc) * 64 + lane) * 8] = f;
}

// =====================================================================
// Kernel C v17: fused scan, TWO DISJOINT LOOPS (the R5-R8 fix).
//  Empirical law from R1-R8: VGPR cap = 65536/block_size (1024thr -> 64).
//  R5-R8 spilled because ONE shared loop made scan bf[] (48) and proj
//  bfr[] (32) + temps co-live (~110 > 64). Fix:
//   - waves 0..7 (scan) and 8..15 (proj) run SEPARATE for-loops with
//     matched barrier counts (wave-uniform branch; s_barrier counts
//     wave arrivals -> legal). Live ranges disjoint: scan ~56 (proven
//     at 512thr), proj ~45.
//   - proj GEMM dieted to 4-frag halves (2 tins per n-tile).
//   - bf[] loaded INSIDE the scan branch, after proj chunk-0 temps die.
//  Scan loop body = R10's verified v11h minus gload staging (proj waves
//  produce Xl in straight [buf][g][tin][d] layout -> xpos perm gone).
//  Eliminates kproj dispatch (+launch gap) and the 96MB wsX round-trip.
// =====================================================================
__global__ __launch_bounds__(1024) void kscan_kernel(
    const float* __restrict__ u_r, const float* __restrict__ u_z,
    const float* __restrict__ u_h, const float* __restrict__ b_r,
    const float* __restrict__ b_z, const float* __restrict__ b_h,
    const int* __restrict__ cor, const float* __restrict__ x,
    const _Float16* __restrict__ wpk, const float* __restrict__ k1k2,
    float* __restrict__ out) {
  const int b = blockIdx.x;
  const int tid = threadIdx.x;
  const int lane = tid & 63;
  const int w = tid >> 6;        // 0..15
  const bool scanw = (w < 8);
  const int pw = w - 8;          // proj wave id 0..7
  const int quad = lane >> 4;
  const int l16 = lane & 15;
  const int q8 = quad * 8;

  __shared__ __align__(16) _Float16 hist[(NL + 1) * NH];   // 32896 B
  __shared__ __align__(16) _Float16 Xl[2 * 3 * CH * ND];   // 24576 B
  __shared__ __align__(16) _Float16 Axt[16 * AXP];         // 8960 B
  __shared__ __align__(16) _Float16 hprev16[2][NH];        // 256 B
  __shared__ float sA[NL];                                 // 1024 B
  __shared__ int sIeff[NL];                                // 1024 B
  __shared__ float k12f[NIN];                              // 1024 B
  // total ~68.1 KB -> 1 block/CU

  const size_t rowb = (size_t)b * NL;

  if (tid < NH) { hprev16[0][tid] = (_Float16)0.f; hist[tid] = (_Float16)0.f; }
  if (tid < NL) {
    const int c = cor[rowb + tid];
    sIeff[tid] = (c == 0) ? tid : c;
  }
  if (tid < NIN) k12f[tid] = k1k2[tid] - k1k2[NIN + tid];

  // ---- proj-wave machinery (live only on proj path) ----
  const int prow0 = 2 * pw;            // chunk-local rows this wave stages
  float4 xrA0, xrB0;                   // staged x rows (one float4/lane)
  f32x4 accP = (f32x4){0.f, 0.f, 0.f, 0.f};  // persists across GEMM halves

  auto LOADX = [&](int t0) {
    const float4* pa = (const float4*)(x + (rowb + t0 + prow0) * NIN + lane * 4);
    const float4* pb = (const float4*)(x + (rowb + t0 + prow0 + 1) * NIN + lane * 4);
    xrA0 = pa[0];
    xrB0 = pb[0];
  };
  auto STAGEX = [&](int t0) {
    f16x4 ha, hb;
    ha[0] = (_Float16)xrA0.x; ha[1] = (_Float16)xrA0.y;
    ha[2] = (_Float16)xrA0.z; ha[3] = (_Float16)xrA0.w;
    hb[0] = (_Float16)xrB0.x; hb[1] = (_Float16)xrB0.y;
    hb[2] = (_Float16)xrB0.z; hb[3] = (_Float16)xrB0.w;
    *(f16x4*)&Axt[prow0 * AXP + lane * 4] = ha;
    *(f16x4*)&Axt[(prow0 + 1) * AXP + lane * 4] = hb;
    const float4 kk = *(const float4*)&k12f[lane * 4];
    float pa = xrA0.x * kk.x + xrA0.y * kk.y + xrA0.z * kk.z + xrA0.w * kk.w;
    float pb = xrB0.x * kk.x + xrB0.y * kk.y + xrB0.z * kk.z + xrB0.w * kk.w;
#pragma unroll
    for (int s = 1; s < 64; s <<= 1) {
      pa += __shfl_xor(pa, s);
      pb += __shfl_xor(pb, s);
    }
    if (lane == 0) {
      sA[t0 + prow0] = 1.f / (1.f + __expf(-pa));
      sA[t0 + prow0 + 1] = 1.f / (1.f + __expf(-pb));
    }
  };
  // One n-tile GEMM in two 4-frag halves (peak 16 B-frag VGPRs).
  auto GEMM_HALF = [&](int i, int half, int buf) {
    const int nt = pw * 3 + i;
    f16x8 bfr[4];
#pragma unroll
    for (int kk = 0; kk < 4; ++kk)
      bfr[kk] = *(const f16x8*)
          &wpk[(((size_t)nt * 8 + half * 4 + kk) * 64 + lane) * 8];
    if (half == 0) accP = (f32x4){0.f, 0.f, 0.f, 0.f};
#pragma unroll
    for (int kk = 0; kk < 4; ++kk) {
      f16x8 af = *(const f16x8*)&Axt[l16 * AXP + (half * 4 + kk) * 32 + q8];
      accP = __builtin_amdgcn_mfma_f32_16x16x32_f16(af, bfr[kk], accP, 0, 0, 0);
    }
    if (half == 1) {
      const int g = nt >> 3;
      const int dblk = nt & 7;
      _Float16* xd = &Xl[((buf * 3 + g) * CH + quad * 4) * ND + dblk * 16 + l16];
#pragma unroll
      for (int r = 0; r < 4; ++r) xd[r * ND] = (_Float16)accP[r];
    }
  };

  // ---- shared prologue: proj waves build chunk 0 (3 matched barriers) ----
  if (!scanw) LOADX(0);
  __syncthreads();                     // k12f / LDS inits visible
  if (!scanw) STAGEX(0);
  __syncthreads();                     // Axt + sA[0..15] visible
  if (!scanw) {
    GEMM_HALF(0, 0, 0); GEMM_HALF(0, 1, 0);
    GEMM_HALF(1, 0, 0); GEMM_HALF(1, 1, 0);
    GEMM_HALF(2, 0, 0); GEMM_HALF(2, 1, 0);
  }
  __syncthreads();                     // Xl buf 0 visible

  if (scanw) {
    // ================= SCAN LOOP (waves 0..7) =================
    // bf loaded HERE: proj chunk-0 temps are dead -> no live overlap.
    f16x8 bf[3][4];
#pragma unroll
    for (int g = 0; g < 3; ++g) {
      const float* ug = (g == 0) ? u_r : (g == 1) ? u_z : u_h;
      const float* base = ug + (size_t)(16 * w + l16) * ND;
#pragma unroll
      for (int kk = 0; kk < 4; ++kk) {
        const float4* p = (const float4*)(base + kk * 32 + q8);
        float4 v0 = p[0], v1 = p[1];
        f16x8 f;
        f[0] = (_Float16)v0.x; f[1] = (_Float16)v0.y;
        f[2] = (_Float16)v0.z; f[3] = (_Float16)v0.w;
        f[4] = (_Float16)v1.x; f[5] = (_Float16)v1.y;
        f[6] = (_Float16)v1.z; f[7] = (_Float16)v1.w;
        bf[g][kk] = f;
      }
    }

    const bool owner = (quad == 0);
    const int d = 16 * w + l16;
    float bbv[3] = {0.f, 0.f, 0.f};
    if (owner) { bbv[0] = b_r[d]; bbv[1] = b_z[d]; bbv[2] = b_h[d]; }

    const f32x4 kZ = (f32x4){0.f, 0.f, 0.f, 0.f};
    float a_c = sA[0];
    int ieff_c = sIeff[0];
    bool pf_c = true;
    float hp = 0.f;
    f32x4 accL[3], accH[3];
#pragma unroll
    for (int g = 0; g < 3; ++g) { accL[g] = kZ; accH[g] = kZ; }

    for (int t = 0; t < NL; ++t) {
      const int par = t & 1;
      const float a = a_c;
      const float oma = 1.f - a;
      const int ieff = ieff_c;
      const int cur = (t >> 4) & 1;
      const int tin = t & 15;

      // ---- late-H path ----
      if (!pf_c) {
        f16x8 g2 = *(const f16x8*)&hist[ieff * NH + q8];
        f16x8 g3 = *(const f16x8*)&hist[ieff * NH + 32 + q8];
#pragma unroll
        for (int g = 0; g < 3; ++g) {
          accH[g] = __builtin_amdgcn_mfma_f32_16x16x32_f16(g2, bf[g][2], kZ, 0, 0, 0);
          accH[g] = __builtin_amdgcn_mfma_f32_16x16x32_f16(g3, bf[g][3], accH[g], 0, 0, 0);
        }
      }

      // ---- L-half (critical): raw h_{t-1} ----
      f16x8 h0 = *(const f16x8*)&hprev16[par][q8];
      f16x8 h1 = *(const f16x8*)&hprev16[par][32 + q8];
#pragma unroll
      for (int g = 0; g < 3; ++g) {
        accL[g] = __builtin_amdgcn_mfma_f32_16x16x32_f16(h0, bf[g][0], kZ, 0, 0, 0);
        accL[g] = __builtin_amdgcn_mfma_f32_16x16x32_f16(h1, bf[g][1], accL[g], 0, 0, 0);
      }

      // ---- X + md (owner lanes; straight Xl layout) ----
      float xv[3], md = 0.f;
      if (owner) {
#pragma unroll
        for (int g = 0; g < 3; ++g)
          xv[g] = (float)Xl[((cur * 3 + g) * CH + tin) * ND + d];
        if (w < 4) {
          md = a * hp;
        } else if (ieff == t) {
          md = oma * hp;
        } else {
          md = oma * (float)hist[ieff * NH + (d - NH)];
        }
      }

      // ---- prefetch step-(t+1) state ----
      const int tn = (t < NL - 1) ? t + 1 : t;
      float a_n = sA[tn];
      int ieff_n = sIeff[tn];
      bool pf_n = (ieff_n <= t);

      // ---- epilogue (owner lanes): a*L + (1-a)*H in f32 ----
      if (owner) {
        float mr = a * accL[0][0] + oma * accH[0][0];
        float mz = a * accL[1][0] + oma * accH[1][0];
        float mh = a * accL[2][0] + oma * accH[2][0];
        float er = __expf(-(xv[0] + bbv[0] + mr));
        float rr = __builtin_amdgcn_rcpf(1.f + er);
        float ez = __expf(-(xv[1] + bbv[1] + mz));
        float zz = __builtin_amdgcn_rcpf(1.f + ez);
        float e2 = __expf(2.f * (xv[2] + bbv[2] + rr * mh));
        float hh = (e2 - 1.f) * __builtin_amdgcn_rcpf(e2 + 1.f);
        float h = md + zz * (hh - md);   // (1-z)*m + z*hh
        hp = h;
        out[(rowb + t) * ND + d] = h;
        if (d < NH) hprev16[par ^ 1][d] = (_Float16)h;
        else        hist[(t + 1) * NH + (d - NH)] = (_Float16)h;
      }

      // ---- pre-issue next step's H half if its hist row is stable ----
      if (pf_n) {
        f16x8 g2 = *(const f16x8*)&hist[ieff_n * NH + q8];
        f16x8 g3 = *(const f16x8*)&hist[ieff_n * NH + 32 + q8];
#pragma unroll
        for (int g = 0; g < 3; ++g) {
          accH[g] = __builtin_amdgcn_mfma_f32_16x16x32_f16(g2, bf[g][2], kZ, 0, 0, 0);
          accH[g] = __builtin_amdgcn_mfma_f32_16x16x32_f16(g3, bf[g][3], accH[g], 0, 0, 0);
        }
      }

      BAR_LDS();
      a_c = a_n; ieff_c = ieff_n; pf_c = pf_n;
    }
  } else {
    // ================= PROJ LOOP (waves 8..15) =================
    for (int t = 0; t < NL; ++t) {
      const int tin = t & 15;
      const int t0n = (t & ~15) + 16;
      if (t0n < NL) {
        const int bufn = (t0n >> 4) & 1;
        if (tin == 0)      LOADX(t0n);
        else if (tin == 2) STAGEX(t0n);
        else if (tin >= 3 && tin <= 8) {
          const int i = (tin - 3) >> 1;
          const int half = (tin - 3) & 1;
          GEMM_HALF(i, half, bufn);
        }
      }
      BAR_LDS();
    }
  }
}

// =====================================================================
extern "C" void kernel_launch(void* const* d_in, const int* in_sizes, int n_in,
                              void* d_out, int out_size, void* d_ws, size_t ws_size,
                              hipStream_t stream) {
  (void)in_sizes; (void)n_in; (void)out_size; (void)ws_size;
  const float* x    = (const float*)d_in[0];
  const int*   cor  = (const int*)d_in[1];
  const float* w_r  = (const float*)d_in[2];
  const float* b_r  = (const float*)d_in[3];
  const float* u_r  = (const float*)d_in[4];
  const float* w_z  = (const float*)d_in[5];
  const float* b_z  = (const float*)d_in[6];
  const float* u_z  = (const float*)d_in[7];
  const float* w_h  = (const float*)d_in[8];
  const float* b_h  = (const float*)d_in[9];
  const float* u_h  = (const float*)d_in[10];
  const float* k1k2 = (const float*)d_in[11];

  _Float16* wpk = (_Float16*)d_ws;   // 192 KB, L2-hot

  kwpack_kernel<<<dim3(24, 8), dim3(64), 0, stream>>>(w_r, w_z, w_h, wpk);
  kscan_kernel<<<dim3(NB), dim3(1024), 0, stream>>>(u_r, u_z, u_h, b_r, b_z,
                                                    b_h, cor, x, wpk, k1k2,
                                                    (float*)d_out);
}

// Round 12
// 239.880 us; speedup vs baseline: 2.8499x; 1.0928x over previous
//
#include <hip/hip_runtime.h>

typedef float f32x4 __attribute__((ext_vector_type(4)));
typedef _Float16 f16x8 __attribute__((ext_vector_type(8)));
typedef _Float16 f16x4 __attribute__((ext_vector_type(4)));
typedef _Float16 f16x2 __attribute__((ext_vector_type(2)));

#define NB 256
#define NL 256
#define NIN 256
#define ND 128
#define NH 64
#define CH 16                        // X-chunk (steps)
#define AXP 280                      // Axt row stride (f16): bank-spread pad

// raw barrier: LDS-only drain + compile-time fence (R10-hardened)
#define BAR_LDS()                                                     \
  do {                                                                \
    asm volatile("s_waitcnt lgkmcnt(0)\n\ts_barrier" ::: "memory");   \
    __builtin_amdgcn_sched_barrier(0);                                \
  } while (0)

// =====================================================================
// Kernel W: pack w_r|w_z|w_h (f32 [128][256]) into f16 fragment order.
// wpk[((nt*8+kc)*64+lane)*8+j] = w_gate[(nt&7)*16+(lane&15)]
//                                 [kc*32+(lane>>4)*8+j];  192 KB, L2-hot.
// =====================================================================
__global__ void kwpack_kernel(const float* __restrict__ w_r,
                              const float* __restrict__ w_z,
                              const float* __restrict__ w_h,
                              _Float16* __restrict__ wpk) {
  const int lane = threadIdx.x;        // 0..63
  const int nt = blockIdx.x;           // 0..23
  const int kc = blockIdx.y;           // 0..7
  const float* wg = (nt < 8) ? w_r : (nt < 16) ? w_z : w_h;
  const int col = (nt & 7) * 16 + (lane & 15);
  const int k0 = kc * 32 + (lane >> 4) * 8;
  const float4* p = (const float4*)(wg + (size_t)col * NIN + k0);
  float4 v0 = p[0], v1 = p[1];
  f16x8 f;
  f[0] = (_Float16)v0.x; f[1] = (_Float16)v0.y;
  f[2] = (_Float16)v0.z; f[3] = (_Float16)v0.w;
  f[4] = (_Float16)v1.x; f[5] = (_Float16)v1.y;
  f[6] = (_Float16)v1.z; f[7] = (_Float16)v1.w;
  *(f16x8*)&wpk[(((size_t)nt * 8 + kc) * 64 + lane) * 8] = f;
}

// =====================================================================
// Kernel C v18: v17 (R11, verified 262us) + BATCHED-H.
//  cor is static and hist rows are immutable once written, so the H-half
//  (hist-row contribution) for all 16 steps of a chunk with
//  ieff <= chunk_start is ONE 6-MFMA batch per chunk: A-frag M-dim holds
//  16 DIFFERENT hist rows (per-lane gather, row = lane&15's ieff);
//  C row tin lands on quad tin>>2 / reg tin&3. L-half A rows are all
//  identical (broadcast hprev) -> every lane/reg holds the L dot, so
//  the epilogue migrates to the rotating owner quad with no shuffles.
//  Steps with recent ieff (> chunk_start, ~12%) use the per-step late-H
//  path. Step loop 4x-unrolled so the accHB reg index tin&3 is
//  compile-time (rule #20). hp carry + pf machinery deleted (md reads
//  LDS uniformly; rows are >=1 barrier old).
//  Per-step scan cost: 12 MFMA + 4 ds_read -> 6 MFMA + 2 ds_read.
// =====================================================================
__global__ __launch_bounds__(1024) void kscan_kernel(
    const float* __restrict__ u_r, const float* __restrict__ u_z,
    const float* __restrict__ u_h, const float* __restrict__ b_r,
    const float* __restrict__ b_z, const float* __restrict__ b_h,
    const int* __restrict__ cor, const float* __restrict__ x,
    const _Float16* __restrict__ wpk, const float* __restrict__ k1k2,
    float* __restrict__ out) {
  const int b = blockIdx.x;
  const int tid = threadIdx.x;
  const int lane = tid & 63;
  const int w = tid >> 6;        // 0..15
  const bool scanw = (w < 8);
  const int pw = w - 8;          // proj wave id 0..7
  const int quad = lane >> 4;
  const int l16 = lane & 15;
  const int q8 = quad * 8;

  __shared__ __align__(16) _Float16 hist[(NL + 1) * NH];   // 32896 B
  __shared__ __align__(16) _Float16 Xl[2 * 3 * CH * ND];   // 24576 B
  __shared__ __align__(16) _Float16 Axt[16 * AXP];         // 8960 B
  __shared__ __align__(16) _Float16 hprev16[2][NH];        // 256 B
  __shared__ float sA[NL];                                 // 1024 B
  __shared__ int sIeff[NL];                                // 1024 B
  __shared__ float k12f[NIN];                              // 1024 B

  const size_t rowb = (size_t)b * NL;

  if (tid < NH) { hprev16[0][tid] = (_Float16)0.f; hist[tid] = (_Float16)0.f; }
  if (tid < NL) {
    const int c = cor[rowb + tid];
    sIeff[tid] = (c == 0) ? tid : c;
  }
  if (tid < NIN) k12f[tid] = k1k2[tid] - k1k2[NIN + tid];

  // ---- proj-wave machinery (live only on proj path) ----
  const int prow0 = 2 * pw;            // chunk-local rows this wave stages
  float4 xrA0, xrB0;                   // staged x rows (one float4/lane)
  f32x4 accP = (f32x4){0.f, 0.f, 0.f, 0.f};  // persists across GEMM halves

  auto LOADX = [&](int t0) {
    const float4* pa = (const float4*)(x + (rowb + t0 + prow0) * NIN + lane * 4);
    const float4* pb = (const float4*)(x + (rowb + t0 + prow0 + 1) * NIN + lane * 4);
    xrA0 = pa[0];
    xrB0 = pb[0];
  };
  auto STAGEX = [&](int t0) {
    f16x4 ha, hb;
    ha[0] = (_Float16)xrA0.x; ha[1] = (_Float16)xrA0.y;
    ha[2] = (_Float16)xrA0.z; ha[3] = (_Float16)xrA0.w;
    hb[0] = (_Float16)xrB0.x; hb[1] = (_Float16)xrB0.y;
    hb[2] = (_Float16)xrB0.z; hb[3] = (_Float16)xrB0.w;
    *(f16x4*)&Axt[prow0 * AXP + lane * 4] = ha;
    *(f16x4*)&Axt[(prow0 + 1) * AXP + lane * 4] = hb;
    const float4 kk = *(const float4*)&k12f[lane * 4];
    float pa = xrA0.x * kk.x + xrA0.y * kk.y + xrA0.z * kk.z + xrA0.w * kk.w;
    float pb = xrB0.x * kk.x + xrB0.y * kk.y + xrB0.z * kk.z + xrB0.w * kk.w;
#pragma unroll
    for (int s = 1; s < 64; s <<= 1) {
      pa += __shfl_xor(pa, s);
      pb += __shfl_xor(pb, s);
    }
    if (lane == 0) {
      sA[t0 + prow0] = 1.f / (1.f + __expf(-pa));
      sA[t0 + prow0 + 1] = 1.f / (1.f + __expf(-pb));
    }
  };
  // One n-tile GEMM in two 4-frag halves (peak 16 B-frag VGPRs).
  auto GEMM_HALF = [&](int i, int half, int buf) {
    const int nt = pw * 3 + i;
    f16x8 bfr[4];
#pragma unroll
    for (int kk = 0; kk < 4; ++kk)
      bfr[kk] = *(const f16x8*)
          &wpk[(((size_t)nt * 8 + half * 4 + kk) * 64 + lane) * 8];
    if (half == 0) accP = (f32x4){0.f, 0.f, 0.f, 0.f};
#pragma unroll
    for (int kk = 0; kk < 4; ++kk) {
      f16x8 af = *(const f16x8*)&Axt[l16 * AXP + (half * 4 + kk) * 32 + q8];
      accP = __builtin_amdgcn_mfma_f32_16x16x32_f16(af, bfr[kk], accP, 0, 0, 0);
    }
    if (half == 1) {
      const int g = nt >> 3;
      const int dblk = nt & 7;
      _Float16* xd = &Xl[((buf * 3 + g) * CH + quad * 4) * ND + dblk * 16 + l16];
#pragma unroll
      for (int r = 0; r < 4; ++r) xd[r * ND] = (_Float16)accP[r];
    }
  };

  // ---- shared prologue: proj waves build chunk 0 (3 matched barriers) ----
  if (!scanw) LOADX(0);
  __syncthreads();                     // k12f / LDS inits visible
  if (!scanw) STAGEX(0);
  __syncthreads();                     // Axt + sA[0..15] visible
  if (!scanw) {
    GEMM_HALF(0, 0, 0); GEMM_HALF(0, 1, 0);
    GEMM_HALF(1, 0, 0); GEMM_HALF(1, 1, 0);
    GEMM_HALF(2, 0, 0); GEMM_HALF(2, 1, 0);
  }
  __syncthreads();                     // Xl buf 0 visible

  if (scanw) {
    // ================= SCAN LOOP (waves 0..7) =================
    f16x8 bf[3][4];
#pragma unroll
    for (int g = 0; g < 3; ++g) {
      const float* ug = (g == 0) ? u_r : (g == 1) ? u_z : u_h;
      const float* base = ug + (size_t)(16 * w + l16) * ND;
#pragma unroll
      for (int kk = 0; kk < 4; ++kk) {
        const float4* p = (const float4*)(base + kk * 32 + q8);
        float4 v0 = p[0], v1 = p[1];
        f16x8 f;
        f[0] = (_Float16)v0.x; f[1] = (_Float16)v0.y;
        f[2] = (_Float16)v0.z; f[3] = (_Float16)v0.w;
        f[4] = (_Float16)v1.x; f[5] = (_Float16)v1.y;
        f[6] = (_Float16)v1.z; f[7] = (_Float16)v1.w;
        bf[g][kk] = f;
      }
    }

    const int d = 16 * w + l16;
    float bbv[3];                      // all lanes (owner quad rotates)
    bbv[0] = b_r[d]; bbv[1] = b_z[d]; bbv[2] = b_h[d];

    const f32x4 kZ = (f32x4){0.f, 0.f, 0.f, 0.f};
    float a_c = sA[0];
    int ieff_c = sIeff[0];
    f32x4 accHB[3];                    // batched-H: C row tin -> quad tin>>2, reg tin&3

    for (int tb = 0; tb < NL; tb += 4) {
      const int cur = (tb >> 4) & 1;
      const int t0 = tb & ~15;         // chunk start
      const int tinb = tb & 15;        // 0,4,8,12

      if (tinb == 0) {
        // ---- batched-H for chunk [t0, t0+16): per-lane hist-row gather ----
        int ie = sIeff[t0 + l16];
        int rv = (ie > t0) ? t0 : ie;  // recent rows patched per-step later
        const _Float16* hrow = &hist[rv * NH];
        f16x8 a0 = *(const f16x8*)&hrow[q8];
        f16x8 a1 = *(const f16x8*)&hrow[32 + q8];
#pragma unroll
        for (int g = 0; g < 3; ++g) {
          accHB[g] = __builtin_amdgcn_mfma_f32_16x16x32_f16(a0, bf[g][2], kZ, 0, 0, 0);
          accHB[g] = __builtin_amdgcn_mfma_f32_16x16x32_f16(a1, bf[g][3], accHB[g], 0, 0, 0);
        }
      }

      const int oq = tinb >> 2;        // owner quad, constant over the 4 steps
      const bool owner = (quad == oq);

#pragma unroll
      for (int j = 0; j < 4; ++j) {
        const int t = tb + j;
        const int par = j & 1;         // == t&1 (tb multiple of 4)
        const int tin = tinb + j;
        const float a = a_c;
        const float oma = 1.f - a;
        const int ieff = ieff_c;
        const bool late = (ieff > t0); // batched row invalid -> per-step H

        // ---- late-H (rare): rows identical -> any lane/reg valid ----
        f32x4 hl0, hl1, hl2;
        if (late) {
          f16x8 g2 = *(const f16x8*)&hist[ieff * NH + q8];
          f16x8 g3 = *(const f16x8*)&hist[ieff * NH + 32 + q8];
          hl0 = __builtin_amdgcn_mfma_f32_16x16x32_f16(g2, bf[0][2], kZ, 0, 0, 0);
          hl0 = __builtin_amdgcn_mfma_f32_16x16x32_f16(g3, bf[0][3], hl0, 0, 0, 0);
          hl1 = __builtin_amdgcn_mfma_f32_16x16x32_f16(g2, bf[1][2], kZ, 0, 0, 0);
          hl1 = __builtin_amdgcn_mfma_f32_16x16x32_f16(g3, bf[1][3], hl1, 0, 0, 0);
          hl2 = __builtin_amdgcn_mfma_f32_16x16x32_f16(g2, bf[2][2], kZ, 0, 0, 0);
          hl2 = __builtin_amdgcn_mfma_f32_16x16x32_f16(g3, bf[2][3], hl2, 0, 0, 0);
        }

        // ---- L-half (critical): broadcast h_{t-1} -> all rows identical ----
        f16x8 h0 = *(const f16x8*)&hprev16[par][q8];
        f16x8 h1 = *(const f16x8*)&hprev16[par][32 + q8];
        f32x4 accL[3];
#pragma unroll
        for (int g = 0; g < 3; ++g) {
          accL[g] = __builtin_amdgcn_mfma_f32_16x16x32_f16(h0, bf[g][0], kZ, 0, 0, 0);
          accL[g] = __builtin_amdgcn_mfma_f32_16x16x32_f16(h1, bf[g][1], accL[g], 0, 0, 0);
        }

        // ---- prefetch step-(t+1) state ----
        const int tn = (t < NL - 1) ? t + 1 : t;
        float a_n = sA[tn];
        int ieff_n = sIeff[tn];

        // ---- epilogue on the owner quad ----
        if (owner) {
          float xv0 = (float)Xl[((cur * 3 + 0) * CH + tin) * ND + d];
          float xv1 = (float)Xl[((cur * 3 + 1) * CH + tin) * ND + d];
          float xv2 = (float)Xl[((cur * 3 + 2) * CH + tin) * ND + d];
          float md;
          if (w < 4) md = a * (float)hprev16[par][d];
          else       md = oma * (float)hist[ieff * NH + (d - NH)];
          float H0 = late ? hl0[0] : accHB[0][j];
          float H1 = late ? hl1[0] : accHB[1][j];
          float H2 = late ? hl2[0] : accHB[2][j];
          float mr = a * accL[0][0] + oma * H0;
          float mz = a * accL[1][0] + oma * H1;
          float mh = a * accL[2][0] + oma * H2;
          float er = __expf(-(xv0 + bbv[0] + mr));
          float rr = __builtin_amdgcn_rcpf(1.f + er);
          float ez = __expf(-(xv1 + bbv[1] + mz));
          float zz = __builtin_amdgcn_rcpf(1.f + ez);
          float e2 = __expf(2.f * (xv2 + bbv[2] + rr * mh));
          float hh = (e2 - 1.f) * __builtin_amdgcn_rcpf(e2 + 1.f);
          float h = md + zz * (hh - md);   // (1-z)*m + z*hh
          out[(rowb + t) * ND + d] = h;
          if (d < NH) hprev16[par ^ 1][d] = (_Float16)h;
          else        hist[(t + 1) * NH + (d - NH)] = (_Float16)h;
        }

        BAR_LDS();
        a_c = a_n; ieff_c = ieff_n;
      }
    }
  } else {
    // ================= PROJ LOOP (waves 8..15) =================
    for (int t = 0; t < NL; ++t) {
      const int tin = t & 15;
      const int t0n = (t & ~15) + 16;
      if (t0n < NL) {
        const int bufn = (t0n >> 4) & 1;
        if (tin == 0)      LOADX(t0n);
        else if (tin == 2) STAGEX(t0n);
        else if (tin >= 3 && tin <= 8) {
          const int i = (tin - 3) >> 1;
          const int half = (tin - 3) & 1;
          GEMM_HALF(i, half, bufn);
        }
      }
      BAR_LDS();
    }
  }
}

// =====================================================================
extern "C" void kernel_launch(void* const* d_in, const int* in_sizes, int n_in,
                              void* d_out, int out_size, void* d_ws, size_t ws_size,
                              hipStream_t stream) {
  (void)in_sizes; (void)n_in; (void)out_size; (void)ws_size;
  const float* x    = (const float*)d_in[0];
  const int*   cor  = (const int*)d_in[1];
  const float* w_r  = (const float*)d_in[2];
  const float* b_r  = (const float*)d_in[3];
  const float* u_r  = (const float*)d_in[4];
  const float* w_z  = (const float*)d_in[5];
  const float* b_z  = (const float*)d_in[6];
  const float* u_z  = (const float*)d_in[7];
  const float* w_h  = (const float*)d_in[8];
  const float* b_h  = (const float*)d_in[9];
  const float* u_h  = (const float*)d_in[10];
  const float* k1k2 = (const float*)d_in[11];

  _Float16* wpk = (_Float16*)d_ws;   // 192 KB, L2-hot

  kwpack_kernel<<<dim3(24, 8), dim3(64), 0, stream>>>(w_r, w_z, w_h, wpk);
  kscan_kernel<<<dim3(NB), dim3(1024), 0, stream>>>(u_r, u_z, u_h, b_r, b_z,
                                                    b_h, cor, x, wpk, k1k2,
                                                    (float*)d_out);
}